// Round 1
// baseline (259.627 us; speedup 1.0000x reference)
//
#include <hip/hip_runtime.h>
#include <math.h>

// CPNet registration: B=8 batches, pc1 (4 x 4096), pc2 (4 x 4096), fp32.
// Outputs: T (8,4,4)=128 | q (8,4)=32 | t (8,3)=24  -> 184 floats concat.

constexpr int cB  = 8;
constexpr int cN1 = 4096;
constexpr int cN2 = 4096;
constexpr int cMC = 4;               // m-chunks for occupancy
constexpr int cCHUNK = cN2 / cMC;    // 1024
constexpr float cEPS  = 1e-5f;
constexpr float cFACT = 2.0f;

// ---------------- workspace layout (bytes) ----------------
// p2pack : float4[cB*cN2]        @ 0         (512 KB)
// partA  : float4[cMC*cB*cN1]    @ 0x080000  (2 MB)
// partM  : float [cMC*cB*cN1]    @ 0x280000  (512 KB)
// near4  : float4[cB*cN1]        @ 0x300000  (512 KB)
constexpr size_t OFF_PARTA = 524288;
constexpr size_t OFF_PARTM = 2621440;
constexpr size_t OFF_NEAR  = 3145728;

// ---------------- kernel A: pack pc2 as (x,y,z,|p|^2) ----------------
__global__ __launch_bounds__(256) void cpnet_pack(
    const float* __restrict__ pc2, float4* __restrict__ p2pack) {
  int idx = blockIdx.x * 256 + threadIdx.x;   // over cB*cN2
  int b = idx >> 12;          // / 4096
  int m = idx & (cN2 - 1);
  const float* base = pc2 + (size_t)b * 4 * cN2;
  float x = base[m], y = base[cN2 + m], z = base[2 * cN2 + m];
  p2pack[idx] = make_float4(x, y, z, x * x + y * y + z * z);
}

// ---------------- kernel B: per-n two-pass softmax partials ----------------
__global__ __launch_bounds__(256) void cpnet_partial(
    const float* __restrict__ pc1, const float4* __restrict__ p2pack,
    float4* __restrict__ partA, float* __restrict__ partM) {
  __shared__ float4 tile[cCHUNK];   // 16 KB
  const int tid = threadIdx.x;
  const int b = blockIdx.z, c = blockIdx.y;
  const int n = blockIdx.x * 256 + tid;

  const float4* src = p2pack + (size_t)b * cN2 + (size_t)c * cCHUNK;
  for (int i = tid; i < cCHUNK; i += 256) tile[i] = src[i];
  __syncthreads();

  const float* p1b = pc1 + (size_t)b * 4 * cN1;
  const float x1 = p1b[n], y1 = p1b[cN1 + n], z1 = p1b[2 * cN1 + n];
  const float n1sq = x1 * x1 + y1 * y1 + z1 * z1;

  // pass 1: row min of d  (s = FACT/max(d,EPS) is non-increasing in d)
  float dmin = 1e30f;
#pragma unroll 8
  for (int m = 0; m < cCHUNK; ++m) {
    float4 v = tile[m];
    float dot = fmaf(x1, v.x, fmaf(y1, v.y, z1 * v.z));
    float d = fmaf(-2.0f, dot, n1sq) + v.w;
    dmin = fminf(dmin, d);
  }
  const float smax = __fdividef(cFACT, fmaxf(dmin, cEPS));

  // pass 2: exp-sum + weighted accumulators (row 3 of pc2 is exactly 1.0)
  float S = 0.f, Ax = 0.f, Ay = 0.f, Az = 0.f;
#pragma unroll 4
  for (int m = 0; m < cCHUNK; ++m) {
    float4 v = tile[m];
    float dot = fmaf(x1, v.x, fmaf(y1, v.y, z1 * v.z));
    float d = fmaf(-2.0f, dot, n1sq) + v.w;
    float s = __fdividef(cFACT, fmaxf(d, cEPS));
    float e = __expf(s - smax);
    S += e;
    Ax = fmaf(e, v.x, Ax);
    Ay = fmaf(e, v.y, Ay);
    Az = fmaf(e, v.z, Az);
  }

  const int idx = (c * cB + b) * cN1 + n;
  partA[idx] = make_float4(Ax, Ay, Az, S);
  partM[idx] = smax;
}

// ---------------- block reduce (256 threads, double) ----------------
__device__ __forceinline__ double block_reduce(double v, double* red, int tid) {
  red[tid] = v;
  __syncthreads();
  for (int s = 128; s > 0; s >>= 1) {
    if (tid < s) red[tid] += red[tid + s];
    __syncthreads();
  }
  double r = red[0];
  __syncthreads();
  return r;
}

// ---------------- kernel C: per-batch finalize ----------------
__global__ __launch_bounds__(256) void cpnet_finalize(
    const float* __restrict__ pc1,
    const float4* __restrict__ partA, const float* __restrict__ partM,
    float4* __restrict__ near4, float* __restrict__ out) {
  const int b = blockIdx.x, tid = threadIdx.x;
  __shared__ double red[256];

  const float* p1b = pc1 + (size_t)b * 4 * cN1;

  // pass A: combine chunk partials -> nearest point + dist; sum dist
  double dsum = 0.0;
  for (int n = tid; n < cN1; n += 256) {
    float m0 = partM[(0 * cB + b) * cN1 + n];
    float m1 = partM[(1 * cB + b) * cN1 + n];
    float m2 = partM[(2 * cB + b) * cN1 + n];
    float m3 = partM[(3 * cB + b) * cN1 + n];
    float g = fmaxf(fmaxf(m0, m1), fmaxf(m2, m3));
    float w0 = __expf(m0 - g), w1 = __expf(m1 - g);
    float w2 = __expf(m2 - g), w3 = __expf(m3 - g);
    float4 a0 = partA[(0 * cB + b) * cN1 + n];
    float4 a1 = partA[(1 * cB + b) * cN1 + n];
    float4 a2 = partA[(2 * cB + b) * cN1 + n];
    float4 a3 = partA[(3 * cB + b) * cN1 + n];
    float S = a0.w * w0 + a1.w * w1 + a2.w * w2 + a3.w * w3;
    float inv = 1.0f / S;
    float nx = (a0.x * w0 + a1.x * w1 + a2.x * w2 + a3.x * w3) * inv;
    float ny = (a0.y * w0 + a1.y * w1 + a2.y * w2 + a3.y * w3) * inv;
    float nz = (a0.z * w0 + a1.z * w1 + a2.z * w2 + a3.z * w3) * inv;
    float x1 = p1b[n], y1 = p1b[cN1 + n], z1 = p1b[2 * cN1 + n];
    float dx = x1 - nx, dy = y1 - ny, dz = z1 - nz;
    float dist = sqrtf(dx * dx + dy * dy + dz * dz);
    near4[b * cN1 + n] = make_float4(nx, ny, nz, dist);
    dsum += (double)dist;
  }
  double mean = block_reduce(dsum, red, tid) / (double)cN1;
  const float meanf = (float)mean;

  // pass B: inlier mask, wsum, centroid sums
  double wsum = 0, s1x = 0, s1y = 0, s1z = 0, s2x = 0, s2y = 0, s2z = 0;
  for (int n = tid; n < cN1; n += 256) {
    float4 nn = near4[b * cN1 + n];
    float ind = 1.0f / (1.0f + __expf((nn.w - meanf - cEPS) * 1e10f));
    float x1 = p1b[n], y1 = p1b[cN1 + n], z1 = p1b[2 * cN1 + n];
    wsum += (double)ind;
    s1x += (double)(ind * x1); s1y += (double)(ind * y1); s1z += (double)(ind * z1);
    s2x += (double)(ind * nn.x); s2y += (double)(ind * nn.y); s2z += (double)(ind * nn.z);
  }
  double W = block_reduce(wsum, red, tid);
  double c1x = block_reduce(s1x, red, tid) / W;
  double c1y = block_reduce(s1y, red, tid) / W;
  double c1z = block_reduce(s1z, red, tid) / W;
  double c2x = block_reduce(s2x, red, tid) / W;
  double c2y = block_reduce(s2y, red, tid) / W;
  double c2z = block_reduce(s2z, red, tid) / W;

  // pass C: H = sum ind^2 (p1-c1)(p2-c2)^T
  double h[9] = {0, 0, 0, 0, 0, 0, 0, 0, 0};
  for (int n = tid; n < cN1; n += 256) {
    float4 nn = near4[b * cN1 + n];
    float ind = 1.0f / (1.0f + __expf((nn.w - meanf - cEPS) * 1e10f));
    double ax = (double)ind * ((double)p1b[n] - c1x);
    double ay = (double)ind * ((double)p1b[cN1 + n] - c1y);
    double az = (double)ind * ((double)p1b[2 * cN1 + n] - c1z);
    double bx = (double)ind * ((double)nn.x - c2x);
    double by = (double)ind * ((double)nn.y - c2y);
    double bz = (double)ind * ((double)nn.z - c2z);
    h[0] += ax * bx; h[1] += ax * by; h[2] += ax * bz;
    h[3] += ay * bx; h[4] += ay * by; h[5] += ay * bz;
    h[6] += az * bx; h[7] += az * by; h[8] += az * bz;
  }
  double H[3][3];
  for (int k = 0; k < 9; ++k) H[k / 3][k % 3] = block_reduce(h[k], red, tid);

  if (tid == 0) {
    // Horn / Besl-McKay 4x4 quaternion matrix
    double trH = H[0][0] + H[1][1] + H[2][2];
    double Nm[4][4], V[4][4];
    Nm[0][0] = trH;
    Nm[0][1] = Nm[1][0] = H[1][2] - H[2][1];
    Nm[0][2] = Nm[2][0] = H[2][0] - H[0][2];
    Nm[0][3] = Nm[3][0] = H[0][1] - H[1][0];
    Nm[1][1] = 2.0 * H[0][0] - trH;
    Nm[1][2] = Nm[2][1] = H[0][1] + H[1][0];
    Nm[1][3] = Nm[3][1] = H[0][2] + H[2][0];
    Nm[2][2] = 2.0 * H[1][1] - trH;
    Nm[2][3] = Nm[3][2] = H[1][2] + H[2][1];
    Nm[3][3] = 2.0 * H[2][2] - trH;

    for (int i = 0; i < 4; ++i)
      for (int j = 0; j < 4; ++j) V[i][j] = (i == j) ? 1.0 : 0.0;
    double sc = 0.0;
    for (int i = 0; i < 4; ++i)
      for (int j = 0; j < 4; ++j) sc += Nm[i][j] * Nm[i][j];

    for (int sweep = 0; sweep < 30; ++sweep) {
      double off = 0.0;
      for (int p = 0; p < 3; ++p)
        for (int q = p + 1; q < 4; ++q) off += Nm[p][q] * Nm[p][q];
      if (off < sc * 1e-30 + 1e-300) break;
      for (int p = 0; p < 3; ++p) {
        for (int q = p + 1; q < 4; ++q) {
          double apq = Nm[p][q];
          if (fabs(apq) < 1e-300) continue;
          double theta = (Nm[q][q] - Nm[p][p]) / (2.0 * apq);
          double tt = (theta >= 0.0 ? 1.0 : -1.0) /
                      (fabs(theta) + sqrt(theta * theta + 1.0));
          double cc = 1.0 / sqrt(tt * tt + 1.0);
          double ss = tt * cc;
          for (int k = 0; k < 4; ++k) {
            double akp = Nm[k][p], akq = Nm[k][q];
            Nm[k][p] = cc * akp - ss * akq;
            Nm[k][q] = ss * akp + cc * akq;
          }
          for (int k = 0; k < 4; ++k) {
            double apk = Nm[p][k], aqk = Nm[q][k];
            Nm[p][k] = cc * apk - ss * aqk;
            Nm[q][k] = ss * apk + cc * aqk;
          }
          for (int k = 0; k < 4; ++k) {
            double vkp = V[k][p], vkq = V[k][q];
            V[k][p] = cc * vkp - ss * vkq;
            V[k][q] = ss * vkp + cc * vkq;
          }
        }
      }
    }
    int imax = 0;
    for (int i = 1; i < 4; ++i)
      if (Nm[i][i] > Nm[imax][imax]) imax = i;
    double qw = V[0][imax], qx = V[1][imax], qy = V[2][imax], qz = V[3][imax];
    double qn = sqrt(qw * qw + qx * qx + qy * qy + qz * qz);
    qw /= qn; qx /= qn; qy /= qn; qz /= qn;

    double R[3][3];
    R[0][0] = 1.0 - 2.0 * (qy * qy + qz * qz);
    R[0][1] = 2.0 * (qx * qy - qw * qz);
    R[0][2] = 2.0 * (qx * qz + qw * qy);
    R[1][0] = 2.0 * (qx * qy + qw * qz);
    R[1][1] = 1.0 - 2.0 * (qx * qx + qz * qz);
    R[1][2] = 2.0 * (qy * qz - qw * qx);
    R[2][0] = 2.0 * (qx * qz - qw * qy);
    R[2][1] = 2.0 * (qy * qz + qw * qx);
    R[2][2] = 1.0 - 2.0 * (qx * qx + qy * qy);

    // safeguard vs convention flip: objective is tr(R H); transpose if better
    double tr1 = 0.0, tr2 = 0.0;
    for (int i = 0; i < 3; ++i)
      for (int j = 0; j < 3; ++j) {
        tr1 += R[i][j] * H[j][i];
        tr2 += R[j][i] * H[j][i];
      }
    if (tr2 > tr1) {
      for (int i = 0; i < 3; ++i)
        for (int j = i + 1; j < 3; ++j) {
          double tmp = R[i][j]; R[i][j] = R[j][i]; R[j][i] = tmp;
        }
    }

    double tx = c2x - (R[0][0] * c1x + R[0][1] * c1y + R[0][2] * c1z);
    double ty = c2y - (R[1][0] * c1x + R[1][1] * c1y + R[1][2] * c1z);
    double tz = c2z - (R[2][0] * c1x + R[2][1] * c1y + R[2][2] * c1z);

    // quaternion via the reference's extraction formula (sign conventions)
    auto sgn = [](double x) { return x >= 0.0 ? 1.0 : -1.0; };
    double oqw = 0.5 * sqrt(fmax(1.0 + R[0][0] + R[1][1] + R[2][2], 1e-12));
    double oqx = 0.5 * sqrt(fmax(1.0 + R[0][0] - R[1][1] - R[2][2], 1e-12)) *
                 sgn(R[2][1] - R[1][2]);
    double oqy = 0.5 * sqrt(fmax(1.0 - R[0][0] + R[1][1] - R[2][2], 1e-12)) *
                 sgn(R[0][2] - R[2][0]);
    double oqz = 0.5 * sqrt(fmax(1.0 - R[0][0] - R[1][1] + R[2][2], 1e-12)) *
                 sgn(R[1][0] - R[0][1]);

    // write T (b*16), q (128 + b*4), t (160 + b*3)
    float* T = out + b * 16;
    T[0]  = (float)R[0][0]; T[1]  = (float)R[0][1]; T[2]  = (float)R[0][2]; T[3]  = (float)tx;
    T[4]  = (float)R[1][0]; T[5]  = (float)R[1][1]; T[6]  = (float)R[1][2]; T[7]  = (float)ty;
    T[8]  = (float)R[2][0]; T[9]  = (float)R[2][1]; T[10] = (float)R[2][2]; T[11] = (float)tz;
    T[12] = 0.f; T[13] = 0.f; T[14] = 0.f; T[15] = 1.f;
    float* Q = out + 128 + b * 4;
    Q[0] = (float)oqw; Q[1] = (float)oqx; Q[2] = (float)oqy; Q[3] = (float)oqz;
    float* Tt = out + 160 + b * 3;
    Tt[0] = (float)tx; Tt[1] = (float)ty; Tt[2] = (float)tz;
  }
}

// ---------------- launch ----------------
extern "C" void kernel_launch(void* const* d_in, const int* in_sizes, int n_in,
                              void* d_out, int out_size, void* d_ws, size_t ws_size,
                              hipStream_t stream) {
  const float* pc1 = (const float*)d_in[0];
  const float* pc2 = (const float*)d_in[1];
  float* out = (float*)d_out;
  char* ws = (char*)d_ws;

  float4* p2pack = (float4*)ws;
  float4* partA  = (float4*)(ws + OFF_PARTA);
  float*  partM  = (float*)(ws + OFF_PARTM);
  float4* near4  = (float4*)(ws + OFF_NEAR);

  cpnet_pack<<<cB * cN2 / 256, 256, 0, stream>>>(pc2, p2pack);
  cpnet_partial<<<dim3(cN1 / 256, cMC, cB), 256, 0, stream>>>(pc1, p2pack, partA, partM);
  cpnet_finalize<<<cB, 256, 0, stream>>>(pc1, partA, partM, near4, out);
}

// Round 2
// 190.052 us; speedup vs baseline: 1.3661x; 1.3661x over previous
//
#include <hip/hip_runtime.h>
#include <math.h>

// CPNet registration: B=8 batches, pc1 (4 x 4096), pc2 (4 x 4096), fp32.
// Outputs: T (8,4,4)=128 | q (8,4)=32 | t (8,3)=24  -> 184 floats concat.
//
// R2: single-pass online softmax in exp2 domain, constants folded into the
// packed pc2 (vx = -ln2*x, vw = (ln2/2)*|p|^2  so  s2 = rcp(dk) and weight
// = exp2(s2 - M) with s2 = log2(e)*FACT/d exactly). cMC=8 for 4 waves/SIMD.
// Finalize: one-pass moment expansion of H + batched shuffle reductions.

constexpr int cB  = 8;
constexpr int cN1 = 4096;
constexpr int cN2 = 4096;
constexpr int cMC = 8;               // m-chunks for occupancy
constexpr int cCHUNK = cN2 / cMC;    // 512
constexpr float cEPS  = 1e-5f;
constexpr float cKK   = 0.34657359027997264f;   // ln2/2 = 1/(FACT*log2(e))
constexpr float cEPSK = cEPS * cKK;             // scaled clamp
constexpr float cUNSC = -1.4426950408889634f;   // -1/ln2 (undo -ln2 packing)

// ---------------- workspace layout (bytes) ----------------
// p2pack : float4[cB*cN2]        @ 0          (512 KB)
// partA  : float4[cMC*cB*cN1]    @ 0x080000   (4 MB)
// partM  : float [cMC*cB*cN1]    @ 0x480000   (1 MB)
// near4  : float4[cB*cN1]        @ 0x580000   (512 KB)
constexpr size_t OFF_PARTA = 0x080000;
constexpr size_t OFF_PARTM = 0x480000;
constexpr size_t OFF_NEAR  = 0x580000;

// ---------------- kernel A: pack pc2 as (-ln2*x, -ln2*y, -ln2*z, kk*|p|^2) --
__global__ __launch_bounds__(256) void cpnet_pack(
    const float* __restrict__ pc2, float4* __restrict__ p2pack) {
  int idx = blockIdx.x * 256 + threadIdx.x;   // over cB*cN2
  int b = idx >> 12;          // / 4096
  int m = idx & (cN2 - 1);
  const float* base = pc2 + (size_t)b * 4 * cN2;
  float x = base[m], y = base[cN2 + m], z = base[2 * cN2 + m];
  p2pack[idx] = make_float4(-2.0f * cKK * x, -2.0f * cKK * y, -2.0f * cKK * z,
                            cKK * (x * x + y * y + z * z));
}

// ---------------- kernel B: single-pass online softmax partials ------------
__global__ __launch_bounds__(256) void cpnet_partial(
    const float* __restrict__ pc1, const float4* __restrict__ p2pack,
    float4* __restrict__ partA, float* __restrict__ partM) {
  __shared__ float4 tile[cCHUNK];   // 8 KB
  const int tid = threadIdx.x;
  const int b = blockIdx.z, c = blockIdx.y;
  const int n = blockIdx.x * 256 + tid;

  const float4* src = p2pack + (size_t)b * cN2 + (size_t)c * cCHUNK;
  for (int i = tid; i < cCHUNK; i += 256) tile[i] = src[i];
  __syncthreads();

  const float* p1b = pc1 + (size_t)b * 4 * cN1;
  const float x1 = p1b[n], y1 = p1b[cN1 + n], z1 = p1b[2 * cN1 + n];
  const float n1k = cKK * (x1 * x1 + y1 * y1 + z1 * z1);

  float M = -3.0e38f, S = 0.f, Ax = 0.f, Ay = 0.f, Az = 0.f;
#pragma unroll 2
  for (int m = 0; m < cCHUNK; ++m) {
    float4 v = tile[m];
    // dk = (ln2/2) * d ;  s2 = 1/dk = log2(e)*FACT/d
    float dk = __builtin_fmaf(x1, v.x,
               __builtin_fmaf(y1, v.y,
               __builtin_fmaf(z1, v.z, n1k + v.w)));
    float s2 = __builtin_amdgcn_rcpf(fmaxf(dk, cEPSK));
    if (s2 > M) {               // rare online-softmax rescale
      float sc = __builtin_amdgcn_exp2f(M - s2);
      S *= sc; Ax *= sc; Ay *= sc; Az *= sc;
      M = s2;
    }
    float e = __builtin_amdgcn_exp2f(s2 - M);
    S += e;
    Ax = __builtin_fmaf(e, v.x, Ax);
    Ay = __builtin_fmaf(e, v.y, Ay);
    Az = __builtin_fmaf(e, v.z, Az);
  }

  const int idx = (c * cB + b) * cN1 + n;
  partA[idx] = make_float4(Ax, Ay, Az, S);
  partM[idx] = M;
}

// ---------------- batched block reduce (256 thr, 4 waves, doubles) ---------
__device__ __forceinline__ void reduce_multi(double* v, int nv, double* lds,
                                             int tid) {
  const int lane = tid & 63, w = tid >> 6;
  for (int i = 0; i < nv; ++i) {
    double x = v[i];
    for (int s = 32; s > 0; s >>= 1) x += __shfl_xor(x, s, 64);
    if (lane == 0) lds[i * 4 + w] = x;
  }
  __syncthreads();
  if (tid < nv)
    lds[tid * 4] = lds[tid * 4] + lds[tid * 4 + 1] + lds[tid * 4 + 2] +
                   lds[tid * 4 + 3];
  __syncthreads();
  for (int i = 0; i < nv; ++i) v[i] = lds[i * 4];
  __syncthreads();
}

// ---------------- kernel C: per-batch finalize -----------------------------
__global__ __launch_bounds__(256) void cpnet_finalize(
    const float* __restrict__ pc1,
    const float4* __restrict__ partA, const float* __restrict__ partM,
    float4* __restrict__ near4, float* __restrict__ out) {
  const int b = blockIdx.x, tid = threadIdx.x;
  __shared__ double lds[32 * 4];

  const float* p1b = pc1 + (size_t)b * 4 * cN1;

  // pass A: combine chunk partials -> nearest point + dist; sum dist
  double acc[23];
  acc[0] = 0.0;
  for (int n = tid; n < cN1; n += 256) {
    float Ms[cMC];
    float g = -3.0e38f;
#pragma unroll
    for (int c = 0; c < cMC; ++c) {
      Ms[c] = partM[(c * cB + b) * cN1 + n];
      g = fmaxf(g, Ms[c]);
    }
    float S = 0.f, nx = 0.f, ny = 0.f, nz = 0.f;
#pragma unroll
    for (int c = 0; c < cMC; ++c) {
      float w = exp2f(Ms[c] - g);
      float4 a = partA[(c * cB + b) * cN1 + n];
      S += a.w * w; nx += a.x * w; ny += a.y * w; nz += a.z * w;
    }
    float inv = cUNSC / S;       // undo -ln2 packing + softmax normalize
    nx *= inv; ny *= inv; nz *= inv;
    float x1 = p1b[n], y1 = p1b[cN1 + n], z1 = p1b[2 * cN1 + n];
    float dx = x1 - nx, dy = y1 - ny, dz = z1 - nz;
    float dist = sqrtf(dx * dx + dy * dy + dz * dz);
    near4[b * cN1 + n] = make_float4(nx, ny, nz, dist);
    acc[0] += (double)dist;
  }
  reduce_multi(acc, 1, lds, tid);
  const float meanf = (float)(acc[0] / (double)cN1);

  // pass B: one-pass moments for centroids + H expansion
  // acc: [0]=Si [1..3]=Si*p1 [4..6]=Si*nn [7]=Si2 [8..10]=Si2*p1
  //      [11..13]=Si2*nn [14..22]=Si2*p1_i*nn_j
  for (int i = 0; i < 23; ++i) acc[i] = 0.0;
  for (int n = tid; n < cN1; n += 256) {
    float4 nn = near4[b * cN1 + n];
    float u = (nn.w - meanf - cEPS) * 1e10f;
    float ind = 1.0f / (1.0f + expf(u));
    double di = (double)ind, di2 = di * di;
    double x1 = (double)p1b[n], y1 = (double)p1b[cN1 + n],
           z1 = (double)p1b[2 * cN1 + n];
    double x2 = (double)nn.x, y2 = (double)nn.y, z2 = (double)nn.z;
    acc[0] += di;
    acc[1] += di * x1;  acc[2] += di * y1;  acc[3] += di * z1;
    acc[4] += di * x2;  acc[5] += di * y2;  acc[6] += di * z2;
    acc[7] += di2;
    acc[8] += di2 * x1;  acc[9] += di2 * y1;  acc[10] += di2 * z1;
    acc[11] += di2 * x2; acc[12] += di2 * y2; acc[13] += di2 * z2;
    acc[14] += di2 * x1 * x2; acc[15] += di2 * x1 * y2; acc[16] += di2 * x1 * z2;
    acc[17] += di2 * y1 * x2; acc[18] += di2 * y1 * y2; acc[19] += di2 * y1 * z2;
    acc[20] += di2 * z1 * x2; acc[21] += di2 * z1 * y2; acc[22] += di2 * z1 * z2;
  }
  reduce_multi(acc, 23, lds, tid);

  if (tid == 0) {
    double W = acc[0];
    double c1[3] = {acc[1] / W, acc[2] / W, acc[3] / W};
    double c2[3] = {acc[4] / W, acc[5] / W, acc[6] / W};
    double H[3][3];
    for (int i = 0; i < 3; ++i)
      for (int j = 0; j < 3; ++j)
        H[i][j] = acc[14 + 3 * i + j] - c2[j] * acc[8 + i] -
                  c1[i] * acc[11 + j] + c1[i] * c2[j] * acc[7];

    // Horn / Besl-McKay 4x4 quaternion matrix -> Jacobi eigen
    double trH = H[0][0] + H[1][1] + H[2][2];
    double Nm[4][4], V[4][4];
    Nm[0][0] = trH;
    Nm[0][1] = Nm[1][0] = H[1][2] - H[2][1];
    Nm[0][2] = Nm[2][0] = H[2][0] - H[0][2];
    Nm[0][3] = Nm[3][0] = H[0][1] - H[1][0];
    Nm[1][1] = 2.0 * H[0][0] - trH;
    Nm[1][2] = Nm[2][1] = H[0][1] + H[1][0];
    Nm[1][3] = Nm[3][1] = H[0][2] + H[2][0];
    Nm[2][2] = 2.0 * H[1][1] - trH;
    Nm[2][3] = Nm[3][2] = H[1][2] + H[2][1];
    Nm[3][3] = 2.0 * H[2][2] - trH;

    for (int i = 0; i < 4; ++i)
      for (int j = 0; j < 4; ++j) V[i][j] = (i == j) ? 1.0 : 0.0;
    double sc = 0.0;
    for (int i = 0; i < 4; ++i)
      for (int j = 0; j < 4; ++j) sc += Nm[i][j] * Nm[i][j];

    for (int sweep = 0; sweep < 30; ++sweep) {
      double off = 0.0;
      for (int p = 0; p < 3; ++p)
        for (int q = p + 1; q < 4; ++q) off += Nm[p][q] * Nm[p][q];
      if (off < sc * 1e-30 + 1e-300) break;
      for (int p = 0; p < 3; ++p) {
        for (int q = p + 1; q < 4; ++q) {
          double apq = Nm[p][q];
          if (fabs(apq) < 1e-300) continue;
          double theta = (Nm[q][q] - Nm[p][p]) / (2.0 * apq);
          double tt = (theta >= 0.0 ? 1.0 : -1.0) /
                      (fabs(theta) + sqrt(theta * theta + 1.0));
          double cc = 1.0 / sqrt(tt * tt + 1.0);
          double ss = tt * cc;
          for (int k = 0; k < 4; ++k) {
            double akp = Nm[k][p], akq = Nm[k][q];
            Nm[k][p] = cc * akp - ss * akq;
            Nm[k][q] = ss * akp + cc * akq;
          }
          for (int k = 0; k < 4; ++k) {
            double apk = Nm[p][k], aqk = Nm[q][k];
            Nm[p][k] = cc * apk - ss * aqk;
            Nm[q][k] = ss * apk + cc * aqk;
          }
          for (int k = 0; k < 4; ++k) {
            double vkp = V[k][p], vkq = V[k][q];
            V[k][p] = cc * vkp - ss * vkq;
            V[k][q] = ss * vkp + cc * vkq;
          }
        }
      }
    }
    int imax = 0;
    for (int i = 1; i < 4; ++i)
      if (Nm[i][i] > Nm[imax][imax]) imax = i;
    double qw = V[0][imax], qx = V[1][imax], qy = V[2][imax], qz = V[3][imax];
    double qn = sqrt(qw * qw + qx * qx + qy * qy + qz * qz);
    qw /= qn; qx /= qn; qy /= qn; qz /= qn;

    double R[3][3];
    R[0][0] = 1.0 - 2.0 * (qy * qy + qz * qz);
    R[0][1] = 2.0 * (qx * qy - qw * qz);
    R[0][2] = 2.0 * (qx * qz + qw * qy);
    R[1][0] = 2.0 * (qx * qy + qw * qz);
    R[1][1] = 1.0 - 2.0 * (qx * qx + qz * qz);
    R[1][2] = 2.0 * (qy * qz - qw * qx);
    R[2][0] = 2.0 * (qx * qz - qw * qy);
    R[2][1] = 2.0 * (qy * qz + qw * qx);
    R[2][2] = 1.0 - 2.0 * (qx * qx + qy * qy);

    // safeguard vs convention flip: objective is tr(R H); transpose if better
    double tr1 = 0.0, tr2 = 0.0;
    for (int i = 0; i < 3; ++i)
      for (int j = 0; j < 3; ++j) {
        tr1 += R[i][j] * H[j][i];
        tr2 += R[j][i] * H[j][i];
      }
    if (tr2 > tr1) {
      for (int i = 0; i < 3; ++i)
        for (int j = i + 1; j < 3; ++j) {
          double tmp = R[i][j]; R[i][j] = R[j][i]; R[j][i] = tmp;
        }
    }

    double tx = c2[0] - (R[0][0] * c1[0] + R[0][1] * c1[1] + R[0][2] * c1[2]);
    double ty = c2[1] - (R[1][0] * c1[0] + R[1][1] * c1[1] + R[1][2] * c1[2]);
    double tz = c2[2] - (R[2][0] * c1[0] + R[2][1] * c1[1] + R[2][2] * c1[2]);

    auto sgn = [](double x) { return x >= 0.0 ? 1.0 : -1.0; };
    double oqw = 0.5 * sqrt(fmax(1.0 + R[0][0] + R[1][1] + R[2][2], 1e-12));
    double oqx = 0.5 * sqrt(fmax(1.0 + R[0][0] - R[1][1] - R[2][2], 1e-12)) *
                 sgn(R[2][1] - R[1][2]);
    double oqy = 0.5 * sqrt(fmax(1.0 - R[0][0] + R[1][1] - R[2][2], 1e-12)) *
                 sgn(R[0][2] - R[2][0]);
    double oqz = 0.5 * sqrt(fmax(1.0 - R[0][0] - R[1][1] + R[2][2], 1e-12)) *
                 sgn(R[1][0] - R[0][1]);

    float* T = out + b * 16;
    T[0]  = (float)R[0][0]; T[1]  = (float)R[0][1]; T[2]  = (float)R[0][2]; T[3]  = (float)tx;
    T[4]  = (float)R[1][0]; T[5]  = (float)R[1][1]; T[6]  = (float)R[1][2]; T[7]  = (float)ty;
    T[8]  = (float)R[2][0]; T[9]  = (float)R[2][1]; T[10] = (float)R[2][2]; T[11] = (float)tz;
    T[12] = 0.f; T[13] = 0.f; T[14] = 0.f; T[15] = 1.f;
    float* Q = out + 128 + b * 4;
    Q[0] = (float)oqw; Q[1] = (float)oqx; Q[2] = (float)oqy; Q[3] = (float)oqz;
    float* Tt = out + 160 + b * 3;
    Tt[0] = (float)tx; Tt[1] = (float)ty; Tt[2] = (float)tz;
  }
}

// ---------------- launch ----------------
extern "C" void kernel_launch(void* const* d_in, const int* in_sizes, int n_in,
                              void* d_out, int out_size, void* d_ws, size_t ws_size,
                              hipStream_t stream) {
  const float* pc1 = (const float*)d_in[0];
  const float* pc2 = (const float*)d_in[1];
  float* out = (float*)d_out;
  char* ws = (char*)d_ws;

  float4* p2pack = (float4*)ws;
  float4* partA  = (float4*)(ws + OFF_PARTA);
  float*  partM  = (float*)(ws + OFF_PARTM);
  float4* near4  = (float4*)(ws + OFF_NEAR);

  cpnet_pack<<<cB * cN2 / 256, 256, 0, stream>>>(pc2, p2pack);
  cpnet_partial<<<dim3(cN1 / 256, cMC, cB), 256, 0, stream>>>(pc1, p2pack,
                                                              partA, partM);
  cpnet_finalize<<<cB, 256, 0, stream>>>(pc1, partA, partM, near4, out);
}

// Round 3
// 153.301 us; speedup vs baseline: 1.6936x; 1.2397x over previous
//
#include <hip/hip_runtime.h>
#include <math.h>

// CPNet registration: B=8 batches, pc1 (4 x 4096), pc2 (4 x 4096), fp32.
// Outputs: T (8,4,4)=128 | q (8,4)=32 | t (8,3)=24  -> 184 floats concat.
//
// R3: branch-free two-pass softmax (dmin pass + weighted pass) with packed
// fp32 (float2 -> v_pk_*_f32), SoA LDS tile, pack fused into partial,
// Jacobi capped at 6 fixed sweeps (was the hidden ~70us serial cost).

typedef float v2f __attribute__((ext_vector_type(2)));

constexpr int cB  = 8;
constexpr int cN1 = 4096;
constexpr int cN2 = 4096;
constexpr int cMC = 8;               // m-chunks for occupancy
constexpr int cCHUNK = cN2 / cMC;    // 512
constexpr float cEPS  = 1e-5f;
constexpr float cKK   = 0.34657359027997264f;   // ln2/2 = 1/(FACT*log2(e))
constexpr float cEPSK = cEPS * cKK;             // scaled clamp
constexpr float cUNSC = -1.4426950408889634f;   // -1/ln2 (undo -ln2 packing)

// ---------------- workspace layout (bytes) ----------------
// partA  : float4[cMC*cB*cN1]    @ 0          (4 MB)
// partM  : float [cMC*cB*cN1]    @ 0x400000   (1 MB)
// near4  : float4[cB*cN1]        @ 0x500000   (512 KB)
constexpr size_t OFF_PARTM = 0x400000;
constexpr size_t OFF_NEAR  = 0x500000;

// ---------------- kernel B: two-pass packed softmax partials ---------------
__global__ __launch_bounds__(256) void cpnet_partial(
    const float* __restrict__ pc1, const float* __restrict__ pc2,
    float4* __restrict__ partA, float* __restrict__ partM) {
  __shared__ float xs[cCHUNK], ys[cCHUNK], zs[cCHUNK], ws[cCHUNK];
  const int tid = threadIdx.x;
  const int b = blockIdx.z, c = blockIdx.y;
  const int n = blockIdx.x * 256 + tid;

  // fused pack: (-ln2*x, -ln2*y, -ln2*z, (ln2/2)*|p|^2)
  const float* p2b = pc2 + (size_t)b * 4 * cN2 + c * cCHUNK;
  for (int i = tid; i < cCHUNK; i += 256) {
    float x = p2b[i], y = p2b[cN2 + i], z = p2b[2 * cN2 + i];
    xs[i] = -2.0f * cKK * x;
    ys[i] = -2.0f * cKK * y;
    zs[i] = -2.0f * cKK * z;
    ws[i] = cKK * (x * x + y * y + z * z);
  }
  __syncthreads();

  const float* p1b = pc1 + (size_t)b * 4 * cN1;
  const float x1 = p1b[n], y1 = p1b[cN1 + n], z1 = p1b[2 * cN1 + n];
  const float n1k = cKK * (x1 * x1 + y1 * y1 + z1 * z1);
  const v2f X1 = {x1, x1}, Y1 = {y1, y1}, Z1 = {z1, z1}, N1K = {n1k, n1k};

  const v2f* xs2 = (const v2f*)xs;
  const v2f* ys2 = (const v2f*)ys;
  const v2f* zs2 = (const v2f*)zs;
  const v2f* ws2 = (const v2f*)ws;

  // pass 1: min dk over chunk (dk = (ln2/2)*d; s2 = rcp(dk) monotone dec.)
  v2f dmin2 = {3.0e38f, 3.0e38f};
#pragma unroll 4
  for (int m = 0; m < cCHUNK / 2; ++m) {
    v2f dk = X1 * xs2[m] + (Y1 * ys2[m] + (Z1 * zs2[m] + (ws2[m] + N1K)));
    dmin2 = __builtin_elementwise_min(dmin2, dk);
  }
  const float dmin = fminf(dmin2.x, dmin2.y);
  const float M = __builtin_amdgcn_rcpf(fmaxf(dmin, cEPSK));
  const v2f M2 = {M, M};
  const v2f EPS2 = {cEPSK, cEPSK};

  // pass 2: exp-sum + weighted accumulators, e = exp2(s2 - M) <= 1
  v2f S2 = {0.f, 0.f}, Ax2 = {0.f, 0.f}, Ay2 = {0.f, 0.f}, Az2 = {0.f, 0.f};
#pragma unroll 4
  for (int m = 0; m < cCHUNK / 2; ++m) {
    v2f vx = xs2[m], vy = ys2[m], vz = zs2[m];
    v2f dk = X1 * vx + (Y1 * vy + (Z1 * vz + (ws2[m] + N1K)));
    dk = __builtin_elementwise_max(dk, EPS2);
    v2f s2v;
    s2v.x = __builtin_amdgcn_rcpf(dk.x);
    s2v.y = __builtin_amdgcn_rcpf(dk.y);
    v2f d2 = s2v - M2;
    v2f e;
    e.x = __builtin_amdgcn_exp2f(d2.x);
    e.y = __builtin_amdgcn_exp2f(d2.y);
    S2 += e;
    Ax2 += e * vx;
    Ay2 += e * vy;
    Az2 += e * vz;
  }

  const int idx = (c * cB + b) * cN1 + n;
  partA[idx] = make_float4(Ax2.x + Ax2.y, Ay2.x + Ay2.y, Az2.x + Az2.y,
                           S2.x + S2.y);
  partM[idx] = M;
}

// ---------------- batched block reduce (256 thr, 4 waves, doubles) ---------
__device__ __forceinline__ void reduce_multi(double* v, int nv, double* lds,
                                             int tid) {
  const int lane = tid & 63, w = tid >> 6;
  for (int i = 0; i < nv; ++i) {
    double x = v[i];
    for (int s = 32; s > 0; s >>= 1) x += __shfl_xor(x, s, 64);
    if (lane == 0) lds[i * 4 + w] = x;
  }
  __syncthreads();
  if (tid < nv)
    lds[tid * 4] = lds[tid * 4] + lds[tid * 4 + 1] + lds[tid * 4 + 2] +
                   lds[tid * 4 + 3];
  __syncthreads();
  for (int i = 0; i < nv; ++i) v[i] = lds[i * 4];
  __syncthreads();
}

// ---------------- kernel C: per-batch finalize -----------------------------
__global__ __launch_bounds__(256) void cpnet_finalize(
    const float* __restrict__ pc1,
    const float4* __restrict__ partA, const float* __restrict__ partM,
    float4* __restrict__ near4, float* __restrict__ out) {
  const int b = blockIdx.x, tid = threadIdx.x;
  __shared__ double lds[32 * 4];

  const float* p1b = pc1 + (size_t)b * 4 * cN1;

  // pass A: combine chunk partials -> nearest point + dist; sum dist
  double acc[23];
  acc[0] = 0.0;
  for (int n = tid; n < cN1; n += 256) {
    float Ms[cMC];
    float g = -3.0e38f;
#pragma unroll
    for (int c = 0; c < cMC; ++c) {
      Ms[c] = partM[(c * cB + b) * cN1 + n];
      g = fmaxf(g, Ms[c]);
    }
    float S = 0.f, nx = 0.f, ny = 0.f, nz = 0.f;
#pragma unroll
    for (int c = 0; c < cMC; ++c) {
      float w = exp2f(Ms[c] - g);
      float4 a = partA[(c * cB + b) * cN1 + n];
      S += a.w * w; nx += a.x * w; ny += a.y * w; nz += a.z * w;
    }
    float inv = cUNSC / S;       // undo -ln2 packing + softmax normalize
    nx *= inv; ny *= inv; nz *= inv;
    float x1 = p1b[n], y1 = p1b[cN1 + n], z1 = p1b[2 * cN1 + n];
    float dx = x1 - nx, dy = y1 - ny, dz = z1 - nz;
    float dist = sqrtf(dx * dx + dy * dy + dz * dz);
    near4[b * cN1 + n] = make_float4(nx, ny, nz, dist);
    acc[0] += (double)dist;
  }
  reduce_multi(acc, 1, lds, tid);
  const float meanf = (float)(acc[0] / (double)cN1);

  // pass B: one-pass moments for centroids + H expansion
  // acc: [0]=Si [1..3]=Si*p1 [4..6]=Si*nn [7]=Si2 [8..10]=Si2*p1
  //      [11..13]=Si2*nn [14..22]=Si2*p1_i*nn_j
  for (int i = 0; i < 23; ++i) acc[i] = 0.0;
  for (int n = tid; n < cN1; n += 256) {
    float4 nn = near4[b * cN1 + n];
    float u = (nn.w - meanf - cEPS) * 1e10f;
    float ind = 1.0f / (1.0f + expf(u));
    double di = (double)ind, di2 = di * di;
    double x1 = (double)p1b[n], y1 = (double)p1b[cN1 + n],
           z1 = (double)p1b[2 * cN1 + n];
    double x2 = (double)nn.x, y2 = (double)nn.y, z2 = (double)nn.z;
    acc[0] += di;
    acc[1] += di * x1;  acc[2] += di * y1;  acc[3] += di * z1;
    acc[4] += di * x2;  acc[5] += di * y2;  acc[6] += di * z2;
    acc[7] += di2;
    acc[8] += di2 * x1;  acc[9] += di2 * y1;  acc[10] += di2 * z1;
    acc[11] += di2 * x2; acc[12] += di2 * y2; acc[13] += di2 * z2;
    acc[14] += di2 * x1 * x2; acc[15] += di2 * x1 * y2; acc[16] += di2 * x1 * z2;
    acc[17] += di2 * y1 * x2; acc[18] += di2 * y1 * y2; acc[19] += di2 * y1 * z2;
    acc[20] += di2 * z1 * x2; acc[21] += di2 * z1 * y2; acc[22] += di2 * z1 * z2;
  }
  reduce_multi(acc, 23, lds, tid);

  if (tid == 0) {
    double W = acc[0];
    double c1[3] = {acc[1] / W, acc[2] / W, acc[3] / W};
    double c2[3] = {acc[4] / W, acc[5] / W, acc[6] / W};
    double H[3][3];
    for (int i = 0; i < 3; ++i)
      for (int j = 0; j < 3; ++j)
        H[i][j] = acc[14 + 3 * i + j] - c2[j] * acc[8 + i] -
                  c1[i] * acc[11 + j] + c1[i] * c2[j] * acc[7];

    // Horn / Besl-McKay 4x4 quaternion matrix -> Jacobi eigen (6 sweeps)
    double trH = H[0][0] + H[1][1] + H[2][2];
    double Nm[4][4], V[4][4];
    Nm[0][0] = trH;
    Nm[0][1] = Nm[1][0] = H[1][2] - H[2][1];
    Nm[0][2] = Nm[2][0] = H[2][0] - H[0][2];
    Nm[0][3] = Nm[3][0] = H[0][1] - H[1][0];
    Nm[1][1] = 2.0 * H[0][0] - trH;
    Nm[1][2] = Nm[2][1] = H[0][1] + H[1][0];
    Nm[1][3] = Nm[3][1] = H[0][2] + H[2][0];
    Nm[2][2] = 2.0 * H[1][1] - trH;
    Nm[2][3] = Nm[3][2] = H[1][2] + H[2][1];
    Nm[3][3] = 2.0 * H[2][2] - trH;

    for (int i = 0; i < 4; ++i)
      for (int j = 0; j < 4; ++j) V[i][j] = (i == j) ? 1.0 : 0.0;

    for (int sweep = 0; sweep < 6; ++sweep) {
      for (int p = 0; p < 3; ++p) {
        for (int q = p + 1; q < 4; ++q) {
          double apq = Nm[p][q];
          if (fabs(apq) < 1e-300) continue;
          double theta = (Nm[q][q] - Nm[p][p]) / (2.0 * apq);
          double tt = (theta >= 0.0 ? 1.0 : -1.0) /
                      (fabs(theta) + sqrt(theta * theta + 1.0));
          double cc = 1.0 / sqrt(tt * tt + 1.0);
          double ss = tt * cc;
          for (int k = 0; k < 4; ++k) {
            double akp = Nm[k][p], akq = Nm[k][q];
            Nm[k][p] = cc * akp - ss * akq;
            Nm[k][q] = ss * akp + cc * akq;
          }
          for (int k = 0; k < 4; ++k) {
            double apk = Nm[p][k], aqk = Nm[q][k];
            Nm[p][k] = cc * apk - ss * aqk;
            Nm[q][k] = ss * apk + cc * aqk;
          }
          for (int k = 0; k < 4; ++k) {
            double vkp = V[k][p], vkq = V[k][q];
            V[k][p] = cc * vkp - ss * vkq;
            V[k][q] = ss * vkp + cc * vkq;
          }
        }
      }
    }
    int imax = 0;
    for (int i = 1; i < 4; ++i)
      if (Nm[i][i] > Nm[imax][imax]) imax = i;
    double qw = V[0][imax], qx = V[1][imax], qy = V[2][imax], qz = V[3][imax];
    double qn = sqrt(qw * qw + qx * qx + qy * qy + qz * qz);
    qw /= qn; qx /= qn; qy /= qn; qz /= qn;

    double R[3][3];
    R[0][0] = 1.0 - 2.0 * (qy * qy + qz * qz);
    R[0][1] = 2.0 * (qx * qy - qw * qz);
    R[0][2] = 2.0 * (qx * qz + qw * qy);
    R[1][0] = 2.0 * (qx * qy + qw * qz);
    R[1][1] = 1.0 - 2.0 * (qx * qx + qz * qz);
    R[1][2] = 2.0 * (qy * qz - qw * qx);
    R[2][0] = 2.0 * (qx * qz - qw * qy);
    R[2][1] = 2.0 * (qy * qz + qw * qx);
    R[2][2] = 1.0 - 2.0 * (qx * qx + qy * qy);

    // safeguard vs convention flip: objective is tr(R H); transpose if better
    double tr1 = 0.0, tr2 = 0.0;
    for (int i = 0; i < 3; ++i)
      for (int j = 0; j < 3; ++j) {
        tr1 += R[i][j] * H[j][i];
        tr2 += R[j][i] * H[j][i];
      }
    if (tr2 > tr1) {
      for (int i = 0; i < 3; ++i)
        for (int j = i + 1; j < 3; ++j) {
          double tmp = R[i][j]; R[i][j] = R[j][i]; R[j][i] = tmp;
        }
    }

    double tx = c2[0] - (R[0][0] * c1[0] + R[0][1] * c1[1] + R[0][2] * c1[2]);
    double ty = c2[1] - (R[1][0] * c1[0] + R[1][1] * c1[1] + R[1][2] * c1[2]);
    double tz = c2[2] - (R[2][0] * c1[0] + R[2][1] * c1[1] + R[2][2] * c1[2]);

    auto sgn = [](double x) { return x >= 0.0 ? 1.0 : -1.0; };
    double oqw = 0.5 * sqrt(fmax(1.0 + R[0][0] + R[1][1] + R[2][2], 1e-12));
    double oqx = 0.5 * sqrt(fmax(1.0 + R[0][0] - R[1][1] - R[2][2], 1e-12)) *
                 sgn(R[2][1] - R[1][2]);
    double oqy = 0.5 * sqrt(fmax(1.0 - R[0][0] + R[1][1] - R[2][2], 1e-12)) *
                 sgn(R[0][2] - R[2][0]);
    double oqz = 0.5 * sqrt(fmax(1.0 - R[0][0] - R[1][1] + R[2][2], 1e-12)) *
                 sgn(R[1][0] - R[0][1]);

    float* T = out + b * 16;
    T[0]  = (float)R[0][0]; T[1]  = (float)R[0][1]; T[2]  = (float)R[0][2]; T[3]  = (float)tx;
    T[4]  = (float)R[1][0]; T[5]  = (float)R[1][1]; T[6]  = (float)R[1][2]; T[7]  = (float)ty;
    T[8]  = (float)R[2][0]; T[9]  = (float)R[2][1]; T[10] = (float)R[2][2]; T[11] = (float)tz;
    T[12] = 0.f; T[13] = 0.f; T[14] = 0.f; T[15] = 1.f;
    float* Q = out + 128 + b * 4;
    Q[0] = (float)oqw; Q[1] = (float)oqx; Q[2] = (float)oqy; Q[3] = (float)oqz;
    float* Tt = out + 160 + b * 3;
    Tt[0] = (float)tx; Tt[1] = (float)ty; Tt[2] = (float)tz;
  }
}

// ---------------- launch ----------------
extern "C" void kernel_launch(void* const* d_in, const int* in_sizes, int n_in,
                              void* d_out, int out_size, void* d_ws, size_t ws_size,
                              hipStream_t stream) {
  const float* pc1 = (const float*)d_in[0];
  const float* pc2 = (const float*)d_in[1];
  float* out = (float*)d_out;
  char* ws = (char*)d_ws;

  float4* partA  = (float4*)ws;
  float*  partM  = (float*)(ws + OFF_PARTM);
  float4* near4  = (float4*)(ws + OFF_NEAR);

  cpnet_partial<<<dim3(cN1 / 256, cMC, cB), 256, 0, stream>>>(pc1, pc2,
                                                              partA, partM);
  cpnet_finalize<<<cB, 256, 0, stream>>>(pc1, partA, partM, near4, out);
}

// Round 6
// 142.704 us; speedup vs baseline: 1.8193x; 1.0743x over previous
//
#include <hip/hip_runtime.h>
#include <math.h>

// CPNet registration: B=8 batches, pc1 (4 x 4096), pc2 (4 x 4096), fp32.
// Outputs: T (8,4,4)=128 | q (8,4)=32 | t (8,3)=24  -> 184 floats concat.
//
// R6: bisection round after two NaN failures (R4 fan-in+sparse, R5
// split+sparse). K1 reverted to the PROVEN R3 kernel verbatim (dense
// two-pass packed softmax, 67us measured). Finalize split into 3 wide
// kernels with NO atomics, NO memset, NO new math -- per-block partials
// summed deterministically downstream. near4 aliases partA chunk 0
// (each K2 thread overwrites its own row slot after reading it).

typedef float v2f __attribute__((ext_vector_type(2)));

constexpr int cB  = 8;
constexpr int cN1 = 4096;
constexpr int cN2 = 4096;
constexpr int cMC = 8;               // m-chunks
constexpr int cCHUNK = cN2 / cMC;    // 512
constexpr int cNB2 = cN1 / 256;      // 16 n-blocks for K2/K3
constexpr float cEPS  = 1e-5f;
constexpr float cKK   = 0.34657359027997264f;   // ln2/2 = 1/(FACT*log2(e))
constexpr float cEPSK = cEPS * cKK;             // scaled clamp
constexpr float cUNSC = -1.4426950408889634f;   // -1/ln2 (undo -ln2 packing)

// ---------------- workspace layout (bytes) ----------------
// partA : float4[cMC*cB*cN1] @ 0         (4 MiB; chunk 0 reused as near4)
// partM : float [cMC*cB*cN1] @ 0x400000  (1 MiB)
// dpart : double[cB*16]      @ 0x500000  (1 KiB)
// mpart : double[cB*16*23]   @ 0x500400  (29.4 KiB)
constexpr size_t OFF_PARTM = 0x400000;
constexpr size_t OFF_DPART = 0x500000;
constexpr size_t OFF_MPART = 0x500400;

// ============ K1: R3's proven two-pass packed softmax partials =============
__global__ __launch_bounds__(256) void cpnet_partial(
    const float* __restrict__ pc1, const float* __restrict__ pc2,
    float4* __restrict__ partA, float* __restrict__ partM) {
  __shared__ float xs[cCHUNK], ys[cCHUNK], zs[cCHUNK], ws[cCHUNK];
  const int tid = threadIdx.x;
  const int b = blockIdx.z, c = blockIdx.y;
  const int n = blockIdx.x * 256 + tid;

  // fused pack: (-ln2*x, -ln2*y, -ln2*z, (ln2/2)*|p|^2)
  const float* p2b = pc2 + (size_t)b * 4 * cN2 + c * cCHUNK;
  for (int i = tid; i < cCHUNK; i += 256) {
    float x = p2b[i], y = p2b[cN2 + i], z = p2b[2 * cN2 + i];
    xs[i] = -2.0f * cKK * x;
    ys[i] = -2.0f * cKK * y;
    zs[i] = -2.0f * cKK * z;
    ws[i] = cKK * (x * x + y * y + z * z);
  }
  __syncthreads();

  const float* p1b = pc1 + (size_t)b * 4 * cN1;
  const float x1 = p1b[n], y1 = p1b[cN1 + n], z1 = p1b[2 * cN1 + n];
  const float n1k = cKK * (x1 * x1 + y1 * y1 + z1 * z1);
  const v2f X1 = {x1, x1}, Y1 = {y1, y1}, Z1 = {z1, z1}, N1K = {n1k, n1k};

  const v2f* xs2 = (const v2f*)xs;
  const v2f* ys2 = (const v2f*)ys;
  const v2f* zs2 = (const v2f*)zs;
  const v2f* ws2 = (const v2f*)ws;

  // pass 1: min dk over chunk (dk = (ln2/2)*d; s2 = rcp(dk) monotone dec.)
  v2f dmin2 = {3.0e38f, 3.0e38f};
#pragma unroll 4
  for (int m = 0; m < cCHUNK / 2; ++m) {
    v2f dk = X1 * xs2[m] + (Y1 * ys2[m] + (Z1 * zs2[m] + (ws2[m] + N1K)));
    dmin2 = __builtin_elementwise_min(dmin2, dk);
  }
  const float dmin = fminf(dmin2.x, dmin2.y);
  const float M = __builtin_amdgcn_rcpf(fmaxf(dmin, cEPSK));
  const v2f M2 = {M, M};
  const v2f EPS2 = {cEPSK, cEPSK};

  // pass 2: exp-sum + weighted accumulators, e = exp2(s2 - M) <= 1
  v2f S2 = {0.f, 0.f}, Ax2 = {0.f, 0.f}, Ay2 = {0.f, 0.f}, Az2 = {0.f, 0.f};
#pragma unroll 4
  for (int m = 0; m < cCHUNK / 2; ++m) {
    v2f vx = xs2[m], vy = ys2[m], vz = zs2[m];
    v2f dk = X1 * vx + (Y1 * vy + (Z1 * vz + (ws2[m] + N1K)));
    dk = __builtin_elementwise_max(dk, EPS2);
    v2f s2v;
    s2v.x = __builtin_amdgcn_rcpf(dk.x);
    s2v.y = __builtin_amdgcn_rcpf(dk.y);
    v2f d2 = s2v - M2;
    v2f e;
    e.x = __builtin_amdgcn_exp2f(d2.x);
    e.y = __builtin_amdgcn_exp2f(d2.y);
    S2 += e;
    Ax2 += e * vx;
    Ay2 += e * vy;
    Az2 += e * vz;
  }

  const int idx = (c * cB + b) * cN1 + n;
  partA[idx] = make_float4(Ax2.x + Ax2.y, Ay2.x + Ay2.y, Az2.x + Az2.y,
                           S2.x + S2.y);
  partM[idx] = M;
}

// ---------------- batched block reduce (256 thr, 4 waves, doubles) ---------
__device__ __forceinline__ void reduce_multi(double* v, int nv, double* lds,
                                             int tid) {
  const int lane = tid & 63, w = tid >> 6;
  for (int i = 0; i < nv; ++i) {
    double x = v[i];
    for (int s = 32; s > 0; s >>= 1) x += __shfl_xor(x, s, 64);
    if (lane == 0) lds[i * 4 + w] = x;
  }
  __syncthreads();
  if (tid < nv)
    lds[tid * 4] = lds[tid * 4] + lds[tid * 4 + 1] + lds[tid * 4 + 2] +
                   lds[tid * 4 + 3];
  __syncthreads();
  for (int i = 0; i < nv; ++i) v[i] = lds[i * 4];
  __syncthreads();
}

// ============ K2: combine chunks -> near4 (aliased) + per-block dist sum ===
__global__ __launch_bounds__(256) void cpnet_combine(
    const float* __restrict__ pc1, float4* partA,
    const float* __restrict__ partM, double* __restrict__ dpart) {
  __shared__ double lds[32 * 4];
  const int tid = threadIdx.x;
  const int bx = blockIdx.x, b = blockIdx.y;
  const int n = bx * 256 + tid;

  float Ms[cMC];
  float g = -3.0e38f;
#pragma unroll
  for (int c = 0; c < cMC; ++c) {
    Ms[c] = partM[(c * cB + b) * cN1 + n];
    g = fmaxf(g, Ms[c]);
  }
  float S = 0.f, nx = 0.f, ny = 0.f, nz = 0.f;
#pragma unroll
  for (int c = 0; c < cMC; ++c) {
    float w = exp2f(Ms[c] - g);
    float4 a = partA[(c * cB + b) * cN1 + n];
    S += a.w * w; nx += a.x * w; ny += a.y * w; nz += a.z * w;
  }
  float inv = cUNSC / S;         // undo -ln2 packing + softmax normalize
  nx *= inv; ny *= inv; nz *= inv;
  const float* p1b = pc1 + (size_t)b * 4 * cN1;
  float dx = p1b[n] - nx, dy = p1b[cN1 + n] - ny, dz = p1b[2 * cN1 + n] - nz;
  float dist = sqrtf(dx * dx + dy * dy + dz * dz);
  // near4 alias: overwrite this row's chunk-0 slot (all reads of it done)
  partA[(0 * cB + b) * cN1 + n] = make_float4(nx, ny, nz, dist);

  double acc[1];
  acc[0] = (double)dist;
  reduce_multi(acc, 1, lds, tid);
  if (tid == 0) dpart[b * cNB2 + bx] = acc[0];
}

// ============ K3: inlier mask + 23 moments, per-block partials =============
__global__ __launch_bounds__(256) void cpnet_moments(
    const float* __restrict__ pc1, const float4* __restrict__ partA,
    const double* __restrict__ dpart, double* __restrict__ mpart) {
  __shared__ double lds[32 * 4];
  const int tid = threadIdx.x;
  const int bx = blockIdx.x, b = blockIdx.y;
  const int n = bx * 256 + tid;

  // deterministic mean: same serial sum in every block
  double dsum = 0.0;
  for (int i = 0; i < cNB2; ++i) dsum += dpart[b * cNB2 + i];
  const float meanf = (float)(dsum * (1.0 / (double)cN1));

  float4 nn = partA[(0 * cB + b) * cN1 + n];   // near4 alias
  float u = (nn.w - meanf - cEPS) * 1e10f;
  float ind = 1.0f / (1.0f + expf(u));
  const float* p1b = pc1 + (size_t)b * 4 * cN1;
  double di = (double)ind, di2 = di * di;
  double x1 = (double)p1b[n], y1 = (double)p1b[cN1 + n],
         z1 = (double)p1b[2 * cN1 + n];
  double x2 = (double)nn.x, y2 = (double)nn.y, z2 = (double)nn.z;

  double a[23];
  a[0] = di;
  a[1] = di * x1;  a[2] = di * y1;  a[3] = di * z1;
  a[4] = di * x2;  a[5] = di * y2;  a[6] = di * z2;
  a[7] = di2;
  a[8]  = di2 * x1;  a[9]  = di2 * y1;  a[10] = di2 * z1;
  a[11] = di2 * x2;  a[12] = di2 * y2;  a[13] = di2 * z2;
  a[14] = di2 * x1 * x2; a[15] = di2 * x1 * y2; a[16] = di2 * x1 * z2;
  a[17] = di2 * y1 * x2; a[18] = di2 * y1 * y2; a[19] = di2 * y1 * z2;
  a[20] = di2 * z1 * x2; a[21] = di2 * z1 * y2; a[22] = di2 * z1 * z2;

  reduce_multi(a, 23, lds, tid);
  if (tid == 0) {
    double* mb = mpart + (size_t)(b * cNB2 + bx) * 23;
    for (int i = 0; i < 23; ++i) mb[i] = a[i];
  }
}

// ============ K4: per-batch Kabsch solve (Horn quaternion, Jacobi) =========
__global__ __launch_bounds__(64) void cpnet_solve(
    const double* __restrict__ mpart, float* __restrict__ out) {
  const int b = blockIdx.x;
  if (threadIdx.x != 0) return;

  double acc[23];
  for (int i = 0; i < 23; ++i) acc[i] = 0.0;
  for (int k = 0; k < cNB2; ++k) {
    const double* mb = mpart + (size_t)(b * cNB2 + k) * 23;
    for (int i = 0; i < 23; ++i) acc[i] += mb[i];
  }

  double W = acc[0];
  double c1[3] = {acc[1] / W, acc[2] / W, acc[3] / W};
  double c2[3] = {acc[4] / W, acc[5] / W, acc[6] / W};
  double H[3][3];
  for (int i = 0; i < 3; ++i)
    for (int j = 0; j < 3; ++j)
      H[i][j] = acc[14 + 3 * i + j] - c2[j] * acc[8 + i] -
                c1[i] * acc[11 + j] + c1[i] * c2[j] * acc[7];

  // Horn / Besl-McKay 4x4 quaternion matrix -> Jacobi eigen (6 sweeps)
  double trH = H[0][0] + H[1][1] + H[2][2];
  double Nm[4][4], V[4][4];
  Nm[0][0] = trH;
  Nm[0][1] = Nm[1][0] = H[1][2] - H[2][1];
  Nm[0][2] = Nm[2][0] = H[2][0] - H[0][2];
  Nm[0][3] = Nm[3][0] = H[0][1] - H[1][0];
  Nm[1][1] = 2.0 * H[0][0] - trH;
  Nm[1][2] = Nm[2][1] = H[0][1] + H[1][0];
  Nm[1][3] = Nm[3][1] = H[0][2] + H[2][0];
  Nm[2][2] = 2.0 * H[1][1] - trH;
  Nm[2][3] = Nm[3][2] = H[1][2] + H[2][1];
  Nm[3][3] = 2.0 * H[2][2] - trH;

  for (int i = 0; i < 4; ++i)
    for (int j = 0; j < 4; ++j) V[i][j] = (i == j) ? 1.0 : 0.0;

  for (int sweep = 0; sweep < 6; ++sweep) {
    for (int p = 0; p < 3; ++p) {
      for (int q = p + 1; q < 4; ++q) {
        double apq = Nm[p][q];
        if (fabs(apq) < 1e-300) continue;
        double theta = (Nm[q][q] - Nm[p][p]) / (2.0 * apq);
        double tt = (theta >= 0.0 ? 1.0 : -1.0) /
                    (fabs(theta) + sqrt(theta * theta + 1.0));
        double cc = 1.0 / sqrt(tt * tt + 1.0);
        double ss = tt * cc;
        for (int k = 0; k < 4; ++k) {
          double akp = Nm[k][p], akq = Nm[k][q];
          Nm[k][p] = cc * akp - ss * akq;
          Nm[k][q] = ss * akp + cc * akq;
        }
        for (int k = 0; k < 4; ++k) {
          double apk = Nm[p][k], aqk = Nm[q][k];
          Nm[p][k] = cc * apk - ss * aqk;
          Nm[q][k] = ss * apk + cc * aqk;
        }
        for (int k = 0; k < 4; ++k) {
          double vkp = V[k][p], vkq = V[k][q];
          V[k][p] = cc * vkp - ss * vkq;
          V[k][q] = ss * vkp + cc * vkq;
        }
      }
    }
  }
  int imax = 0;
  for (int i = 1; i < 4; ++i)
    if (Nm[i][i] > Nm[imax][imax]) imax = i;
  double qw = V[0][imax], qx = V[1][imax], qy = V[2][imax], qz = V[3][imax];
  double qn = sqrt(qw * qw + qx * qx + qy * qy + qz * qz);
  qw /= qn; qx /= qn; qy /= qn; qz /= qn;

  double R[3][3];
  R[0][0] = 1.0 - 2.0 * (qy * qy + qz * qz);
  R[0][1] = 2.0 * (qx * qy - qw * qz);
  R[0][2] = 2.0 * (qx * qz + qw * qy);
  R[1][0] = 2.0 * (qx * qy + qw * qz);
  R[1][1] = 1.0 - 2.0 * (qx * qx + qz * qz);
  R[1][2] = 2.0 * (qy * qz - qw * qx);
  R[2][0] = 2.0 * (qx * qz - qw * qy);
  R[2][1] = 2.0 * (qy * qz + qw * qx);
  R[2][2] = 1.0 - 2.0 * (qx * qx + qy * qy);

  // safeguard vs convention flip: objective is tr(R H); transpose if better
  double tr1 = 0.0, tr2 = 0.0;
  for (int i = 0; i < 3; ++i)
    for (int j = 0; j < 3; ++j) {
      tr1 += R[i][j] * H[j][i];
      tr2 += R[j][i] * H[j][i];
    }
  if (tr2 > tr1) {
    for (int i = 0; i < 3; ++i)
      for (int j = i + 1; j < 3; ++j) {
        double tmp = R[i][j]; R[i][j] = R[j][i]; R[j][i] = tmp;
      }
  }

  double tx = c2[0] - (R[0][0] * c1[0] + R[0][1] * c1[1] + R[0][2] * c1[2]);
  double ty = c2[1] - (R[1][0] * c1[0] + R[1][1] * c1[1] + R[1][2] * c1[2]);
  double tz = c2[2] - (R[2][0] * c1[0] + R[2][1] * c1[1] + R[2][2] * c1[2]);

  auto sgn = [](double x) { return x >= 0.0 ? 1.0 : -1.0; };
  double oqw = 0.5 * sqrt(fmax(1.0 + R[0][0] + R[1][1] + R[2][2], 1e-12));
  double oqx = 0.5 * sqrt(fmax(1.0 + R[0][0] - R[1][1] - R[2][2], 1e-12)) *
               sgn(R[2][1] - R[1][2]);
  double oqy = 0.5 * sqrt(fmax(1.0 - R[0][0] + R[1][1] - R[2][2], 1e-12)) *
               sgn(R[0][2] - R[2][0]);
  double oqz = 0.5 * sqrt(fmax(1.0 - R[0][0] - R[1][1] + R[2][2], 1e-12)) *
               sgn(R[1][0] - R[0][1]);

  float* T = out + b * 16;
  T[0]  = (float)R[0][0]; T[1]  = (float)R[0][1]; T[2]  = (float)R[0][2]; T[3]  = (float)tx;
  T[4]  = (float)R[1][0]; T[5]  = (float)R[1][1]; T[6]  = (float)R[1][2]; T[7]  = (float)ty;
  T[8]  = (float)R[2][0]; T[9]  = (float)R[2][1]; T[10] = (float)R[2][2]; T[11] = (float)tz;
  T[12] = 0.f; T[13] = 0.f; T[14] = 0.f; T[15] = 1.f;
  float* Q = out + 128 + b * 4;
  Q[0] = (float)oqw; Q[1] = (float)oqx; Q[2] = (float)oqy; Q[3] = (float)oqz;
  float* Tt = out + 160 + b * 3;
  Tt[0] = (float)tx; Tt[1] = (float)ty; Tt[2] = (float)tz;
}

// ---------------- launch ----------------
extern "C" void kernel_launch(void* const* d_in, const int* in_sizes, int n_in,
                              void* d_out, int out_size, void* d_ws, size_t ws_size,
                              hipStream_t stream) {
  const float* pc1 = (const float*)d_in[0];
  const float* pc2 = (const float*)d_in[1];
  float* out = (float*)d_out;
  char* ws = (char*)d_ws;

  float4* partA = (float4*)ws;
  float*  partM = (float*)(ws + OFF_PARTM);
  double* dpart = (double*)(ws + OFF_DPART);
  double* mpart = (double*)(ws + OFF_MPART);

  cpnet_partial<<<dim3(cN1 / 256, cMC, cB), 256, 0, stream>>>(pc1, pc2,
                                                              partA, partM);
  cpnet_combine<<<dim3(cNB2, cB), 256, 0, stream>>>(pc1, partA, partM, dpart);
  cpnet_moments<<<dim3(cNB2, cB), 256, 0, stream>>>(pc1, partA, dpart, mpart);
  cpnet_solve<<<cB, 64, 0, stream>>>(mpart, out);
}